// Round 3
// baseline (3992.635 us; speedup 1.0000x reference)
//
#include <hip/hip_runtime.h>
#include <math.h>

namespace {
constexpr int Bn = 4;
constexpr int Cn = 512;
constexpr int Ln = 4096;   // 64*64
constexpr float kEps = 1e-5f;

// ---------------- workspace layout (floats) ----------------
constexpr size_t OFF_VT    = 0;                         // [B][L][C] V transposed
constexpr size_t OFF_QT    = OFF_VT + (size_t)Bn*Ln*Cn; // [B][L][C] Q_guide; becomes O
constexpr size_t OFF_MEANS = OFF_QT + (size_t)Bn*Ln*Cn; // [B][C]
constexpr size_t OFF_RSTDS = OFF_MEANS + Bn*Cn;
constexpr size_t OFF_MEANC = OFF_RSTDS + Bn*Cn;
constexpr size_t OFF_RSTDC = OFF_MEANC + Bn*Cn;
constexpr size_t OFF_KP    = OFF_RSTDC + Bn*Cn;         // [B][L] key_pool -> weights
constexpr size_t OFF_GSV   = OFF_KP + (size_t)Bn*Ln;    // [B][C]
constexpr size_t OFF_H1    = OFF_GSV + Bn*Cn;
constexpr size_t OFF_H2    = OFF_H1 + Bn*Cn;
constexpr size_t OFF_GAMMA = OFF_H2 + Bn*Cn;
constexpr size_t OFF_BETA  = OFF_GAMMA + Bn*Cn;
} // namespace

// ---- per-(b,c) mean & rstd over L, ddof=1 ----
__global__ __launch_bounds__(256) void stats_kernel(const float* __restrict__ x,
                                                    float* __restrict__ mean,
                                                    float* __restrict__ rstd) {
    int bc = blockIdx.x;
    const float* row = x + (size_t)bc * Ln;
    float s1 = 0.f, s2 = 0.f;
    for (int i = threadIdx.x; i < Ln; i += 256) {
        float v = row[i];
        s1 += v; s2 += v * v;
    }
    for (int off = 32; off; off >>= 1) {
        s1 += __shfl_down(s1, off);
        s2 += __shfl_down(s2, off);
    }
    __shared__ float a1[4], a2[4];
    int wid = threadIdx.x >> 6;
    if ((threadIdx.x & 63) == 0) { a1[wid] = s1; a2[wid] = s2; }
    __syncthreads();
    if (threadIdx.x == 0) {
        s1 = a1[0] + a1[1] + a1[2] + a1[3];
        s2 = a2[0] + a2[1] + a2[2] + a2[3];
        float m = s1 / Ln;
        float var = (s2 - m * s1) / (Ln - 1);
        mean[bc] = m;
        rstd[bc] = 1.0f / sqrtf(var + kEps);
    }
}

// ---- conv1x1 as tiled GEMM: out = W(CxC) @ Xn(b)(CxL) + bias ----
// NORM: normalize X rows with (x-mean)*rstd.  TRANS: write out as [b][l][c].
template <bool NORM, bool TRANS>
__global__ __launch_bounds__(256) void conv_kernel(const float* __restrict__ X,
                                                   const float* __restrict__ W,
                                                   const float* __restrict__ bias,
                                                   const float* __restrict__ mean,
                                                   const float* __restrict__ rstd,
                                                   float* __restrict__ out) {
    int b = blockIdx.z;
    int o0 = blockIdx.y * 64;
    int l0 = blockIdx.x * 64;
    int tid = threadIdx.x;
    const size_t bCL = (size_t)b * Cn * Ln;
    const size_t bLC = (size_t)b * Ln * Cn;

    __shared__ float Ws[64][17];
    __shared__ float Xs[16][68];

    int ty = tid >> 4;   // 0..15 -> o = 4*ty + i
    int tx = tid & 15;   // 0..15 -> l = tx + 16*j

    float acc[4][4];
#pragma unroll
    for (int i = 0; i < 4; i++)
#pragma unroll
        for (int j = 0; j < 4; j++) acc[i][j] = 0.f;

    for (int cc = 0; cc < Cn; cc += 16) {
        // stage W tile: 64 o x 16 k
        {
            int o = tid >> 2, kf = (tid & 3) * 4;
            float4 w4 = *(const float4*)(W + (size_t)(o0 + o) * Cn + cc + kf);
            Ws[o][kf + 0] = w4.x; Ws[o][kf + 1] = w4.y;
            Ws[o][kf + 2] = w4.z; Ws[o][kf + 3] = w4.w;
        }
        // stage X tile: 16 k x 64 l
        {
            int k = tid >> 4, lf = (tid & 15) * 4;
            float4 x4 = *(const float4*)(X + bCL + (size_t)(cc + k) * Ln + l0 + lf);
            if constexpr (NORM) {
                float mm = mean[b * Cn + cc + k];
                float rr = rstd[b * Cn + cc + k];
                x4.x = (x4.x - mm) * rr; x4.y = (x4.y - mm) * rr;
                x4.z = (x4.z - mm) * rr; x4.w = (x4.w - mm) * rr;
            }
            Xs[k][lf + 0] = x4.x; Xs[k][lf + 1] = x4.y;
            Xs[k][lf + 2] = x4.z; Xs[k][lf + 3] = x4.w;
        }
        __syncthreads();
#pragma unroll
        for (int k = 0; k < 16; k++) {
            float a[4], x[4];
#pragma unroll
            for (int i = 0; i < 4; i++) a[i] = Ws[4 * ty + i][k];
#pragma unroll
            for (int j = 0; j < 4; j++) x[j] = Xs[k][tx + 16 * j];
#pragma unroll
            for (int i = 0; i < 4; i++)
#pragma unroll
                for (int j = 0; j < 4; j++) acc[i][j] += a[i] * x[j];
        }
        __syncthreads();
    }
#pragma unroll
    for (int i = 0; i < 4; i++) {
        int o = o0 + 4 * ty + i;
        float bv = bias[o];
#pragma unroll
        for (int j = 0; j < 4; j++) {
            int l = l0 + tx + 16 * j;
            float v = acc[i][j] + bv;
            if constexpr (TRANS)
                out[bLC + (size_t)l * Cn + o] = v;
            else
                out[bCL + (size_t)o * Ln + l] = v;
        }
    }
}

// ---- key_pool[b,l] = sum_c vsp_w[c]*mvn(style)[b,c,l] + vsp_b ----
__global__ __launch_bounds__(256) void keypool_kernel(const float* __restrict__ style,
                                                      const float* __restrict__ vsp_w,
                                                      const float* __restrict__ vsp_b,
                                                      const float* __restrict__ mean_s,
                                                      const float* __restrict__ rstd_s,
                                                      float* __restrict__ kp) {
    int b = blockIdx.y;
    int l = blockIdx.x * 256 + threadIdx.x;
    const size_t bCL = (size_t)b * Cn * Ln;
    float acc = 0.f;
    for (int c = 0; c < Cn; c++) {
        float v = style[bCL + (size_t)c * Ln + l];
        acc += vsp_w[c] * (v - mean_s[b * Cn + c]) * rstd_s[b * Cn + c];
    }
    kp[b * Ln + l] = acc + vsp_b[0];
}

// ---- softmax over L per b, in place ----
__global__ __launch_bounds__(1024) void softmax_kp_kernel(float* __restrict__ kp) {
    int b = blockIdx.x;
    float* p = kp + (size_t)b * Ln;
    int tid = threadIdx.x;
    float v[4];
    float m = -3e38f;
#pragma unroll
    for (int j = 0; j < 4; j++) { v[j] = p[tid + 1024 * j]; m = fmaxf(m, v[j]); }
    __shared__ float red[16];
    for (int off = 32; off; off >>= 1) m = fmaxf(m, __shfl_down(m, off));
    if ((tid & 63) == 0) red[tid >> 6] = m;
    __syncthreads();
    if (tid == 0) {
        float mm = red[0];
        for (int i = 1; i < 16; i++) mm = fmaxf(mm, red[i]);
        red[0] = mm;
    }
    __syncthreads();
    m = red[0];
    __syncthreads();
    float e[4]; float s = 0.f;
#pragma unroll
    for (int j = 0; j < 4; j++) { e[j] = __expf(v[j] - m); s += e[j]; }
    for (int off = 32; off; off >>= 1) s += __shfl_down(s, off);
    if ((tid & 63) == 0) red[tid >> 6] = s;
    __syncthreads();
    if (tid == 0) {
        float ss = 0.f;
        for (int i = 0; i < 16; i++) ss += red[i];
        red[0] = ss;
    }
    __syncthreads();
    float inv = 1.0f / red[0];
#pragma unroll
    for (int j = 0; j < 4; j++) p[tid + 1024 * j] = e[j] * inv;
}

// ---- gsv[b,c] = sum_l Vt[b,l,c]*w[b,l] ----
__global__ __launch_bounds__(256) void gsv_kernel(const float* __restrict__ Vt,
                                                  const float* __restrict__ w,
                                                  float* __restrict__ gsv) {
    int b = blockIdx.y;
    int cl = threadIdx.x & 31;
    int c = blockIdx.x * 32 + cl;
    int lg = threadIdx.x >> 5;   // 0..7
    float acc = 0.f;
    const size_t bLC = (size_t)b * Ln * Cn;
    for (int l = lg; l < Ln; l += 8)
        acc += Vt[bLC + (size_t)l * Cn + c] * w[b * Ln + l];
    __shared__ float red[8][33];
    red[lg][cl] = acc;
    __syncthreads();
    if (threadIdx.x < 32) {
        float s = 0.f;
        for (int g = 0; g < 8; g++) s += red[g][threadIdx.x];
        gsv[b * Cn + blockIdx.x * 32 + threadIdx.x] = s;
    }
}

// ---- MLP stage 1: h = relu(W1 @ gsv + b1) for both branches ----
__global__ __launch_bounds__(256) void mlp_hidden_kernel(const float* __restrict__ gsv,
                                                         const float* __restrict__ w1a, const float* __restrict__ b1a,
                                                         const float* __restrict__ w1b, const float* __restrict__ b1b,
                                                         float* __restrict__ h1, float* __restrict__ h2) {
    int idx = blockIdx.x * 256 + threadIdx.x;   // B*C
    int b = idx / Cn, c = idx % Cn;
    float a1 = b1a[c], a2 = b1b[c];
    for (int k = 0; k < Cn; k++) {
        float g = gsv[b * Cn + k];
        a1 += w1a[(size_t)c * Cn + k] * g;
        a2 += w1b[(size_t)c * Cn + k] * g;
    }
    h1[idx] = fmaxf(a1, 0.f);
    h2[idx] = fmaxf(a2, 0.f);
}

// ---- MLP stage 2: gamma = W2a @ h1 + b2a ; beta = W2b @ h2 + b2b ----
__global__ __launch_bounds__(256) void mlp_out_kernel(const float* __restrict__ h1, const float* __restrict__ h2,
                                                      const float* __restrict__ w2a, const float* __restrict__ b2a,
                                                      const float* __restrict__ w2b, const float* __restrict__ b2b,
                                                      float* __restrict__ gamma, float* __restrict__ beta) {
    int idx = blockIdx.x * 256 + threadIdx.x;
    int b = idx / Cn, c = idx % Cn;
    float a1 = b2a[c], a2 = b2b[c];
    for (int k = 0; k < Cn; k++) {
        a1 += w2a[(size_t)c * Cn + k] * h1[b * Cn + k];
        a2 += w2b[(size_t)c * Cn + k] * h2[b * Cn + k];
    }
    gamma[idx] = a1;
    beta[idx] = a2;
}

// ---- flash attention: Q-tile 32 rows, K-tile 64 cols, online softmax ----
// Qt [B][L][C] holds Q_guide; gamma/beta applied on load; O overwrites Qt rows.
__global__ __launch_bounds__(256) void flash_kernel(float* __restrict__ Qt,
                                                    const float* __restrict__ Kk,   // [B][C][L]
                                                    const float* __restrict__ Vt,   // [B][L][C]
                                                    const float* __restrict__ gamma,
                                                    const float* __restrict__ beta) {
    int b = blockIdx.y;
    int q0 = blockIdx.x * 32;
    int tid = threadIdx.x;

    __shared__ float Qc[32][68];
    __shared__ float Ks[64][68];
    __shared__ float Ps[32][68];
    __shared__ float Vs[16][260];
    __shared__ float mrow[32], lrow[32], srow[32];

    if (tid < 32) { mrow[tid] = -3e38f; lrow[tid] = 0.f; }

    int qy = tid >> 5;   // 0..7 -> q = qy*4 + i (PV/O)
    int cx = tid & 31;   // c = ch*256 + 32*j + cx
    int ty = tid >> 4;   // 0..15 -> q = 2*ty + i (E)
    int tx = tid & 15;   // k = 4*tx + j

    float o[4][16];
#pragma unroll
    for (int i = 0; i < 4; i++)
#pragma unroll
        for (int j = 0; j < 16; j++) o[i][j] = 0.f;

    const size_t bLC = (size_t)b * Ln * Cn;
    const size_t bCL = (size_t)b * Cn * Ln;

    for (int kt = 0; kt < Ln; kt += 64) {
        // ---------- energy tile E[32][64] ----------
        float e[2][4] = {{0.f, 0.f, 0.f, 0.f}, {0.f, 0.f, 0.f, 0.f}};
        for (int cc = 0; cc < Cn; cc += 64) {
            {   // stage Q chunk (32 rows x 64 cols) with (1+gamma)*q + beta
                int r = tid >> 3, cf = (tid & 7) * 8;
                const float* qp = Qt + bLC + (size_t)(q0 + r) * Cn + cc + cf;
                const float* gp = gamma + b * Cn + cc + cf;
                const float* bp = beta + b * Cn + cc + cf;
                float4 qv0 = *(const float4*)(qp);
                float4 qv1 = *(const float4*)(qp + 4);
                float4 gv0 = *(const float4*)(gp);
                float4 gv1 = *(const float4*)(gp + 4);
                float4 bv0 = *(const float4*)(bp);
                float4 bv1 = *(const float4*)(bp + 4);
                Qc[r][cf + 0] = qv0.x * (1.f + gv0.x) + bv0.x;
                Qc[r][cf + 1] = qv0.y * (1.f + gv0.y) + bv0.y;
                Qc[r][cf + 2] = qv0.z * (1.f + gv0.z) + bv0.z;
                Qc[r][cf + 3] = qv0.w * (1.f + gv0.w) + bv0.w;
                Qc[r][cf + 4] = qv1.x * (1.f + gv1.x) + bv1.x;
                Qc[r][cf + 5] = qv1.y * (1.f + gv1.y) + bv1.y;
                Qc[r][cf + 6] = qv1.z * (1.f + gv1.z) + bv1.z;
                Qc[r][cf + 7] = qv1.w * (1.f + gv1.w) + bv1.w;
            }
            {   // stage K chunk (64 c-rows x 64 k-cols)
                int r = tid >> 2, kf0 = (tid & 3) * 16;
                const float* kpr = Kk + bCL + (size_t)(cc + r) * Ln + kt + kf0;
#pragma unroll
                for (int u = 0; u < 4; u++) {
                    float4 kv = *(const float4*)(kpr + 4 * u);
                    Ks[r][kf0 + 4 * u + 0] = kv.x;
                    Ks[r][kf0 + 4 * u + 1] = kv.y;
                    Ks[r][kf0 + 4 * u + 2] = kv.z;
                    Ks[r][kf0 + 4 * u + 3] = kv.w;
                }
            }
            __syncthreads();
#pragma unroll 4
            for (int c2 = 0; c2 < 64; c2++) {
                float qa0 = Qc[2 * ty + 0][c2];
                float qa1 = Qc[2 * ty + 1][c2];
#pragma unroll
                for (int j = 0; j < 4; j++) {
                    float kb = Ks[c2][4 * tx + j];
                    e[0][j] += qa0 * kb;
                    e[1][j] += qa1 * kb;
                }
            }
            __syncthreads();
        }
#pragma unroll
        for (int i = 0; i < 2; i++)
#pragma unroll
            for (int j = 0; j < 4; j++) Ps[2 * ty + i][4 * tx + j] = e[i][j];
        __syncthreads();

        // ---------- online softmax row update ----------
        if (tid < 32) {
            float mold = mrow[tid];
            float mloc = -3e38f;
            for (int k = 0; k < 64; k++) mloc = fmaxf(mloc, Ps[tid][k]);
            float mnew = fmaxf(mold, mloc);
            float sc = __expf(mold - mnew);
            float sum = 0.f;
            for (int k = 0; k < 64; k++) {
                float pv = __expf(Ps[tid][k] - mnew);
                Ps[tid][k] = pv;
                sum += pv;
            }
            mrow[tid] = mnew;
            lrow[tid] = lrow[tid] * sc + sum;
            srow[tid] = sc;
        }
        __syncthreads();

        // ---------- rescale O ----------
        float sci[4];
#pragma unroll
        for (int i = 0; i < 4; i++) sci[i] = srow[qy * 4 + i];
#pragma unroll
        for (int i = 0; i < 4; i++)
#pragma unroll
            for (int j = 0; j < 16; j++) o[i][j] *= sci[i];

        // ---------- PV: O[32][512] += P[32][64] @ Vt[kt..][c] ----------
        for (int kq = 0; kq < 4; kq++) {
            for (int ch = 0; ch < 2; ch++) {
                {
                    int c4 = (tid & 63) * 4;
                    int kk = tid >> 6;
#pragma unroll
                    for (int r = 0; r < 4; r++) {
                        int krow = kk * 4 + r;
                        float4 v4 = *(const float4*)(Vt + bLC + (size_t)(kt + kq * 16 + krow) * Cn + ch * 256 + c4);
                        Vs[krow][c4 + 0] = v4.x; Vs[krow][c4 + 1] = v4.y;
                        Vs[krow][c4 + 2] = v4.z; Vs[krow][c4 + 3] = v4.w;
                    }
                }
                __syncthreads();
#pragma unroll
                for (int k2 = 0; k2 < 16; k2++) {
                    float pr[4];
#pragma unroll
                    for (int i = 0; i < 4; i++) pr[i] = Ps[qy * 4 + i][kq * 16 + k2];
#pragma unroll
                    for (int j = 0; j < 8; j++) {
                        float v = Vs[k2][32 * j + cx];
#pragma unroll
                        for (int i = 0; i < 4; i++) o[i][ch * 8 + j] += pr[i] * v;
                    }
                }
                __syncthreads();
            }
        }
    }

    // ---------- finalize: O /= l, write back into Qt rows ----------
    float linv[4];
#pragma unroll
    for (int i = 0; i < 4; i++) linv[i] = 1.f / lrow[qy * 4 + i];
#pragma unroll
    for (int i = 0; i < 4; i++) {
        int q = q0 + qy * 4 + i;
#pragma unroll
        for (int jj = 0; jj < 16; jj++) {
            int ch = jj >> 3, j = jj & 7;
            Qt[bLC + (size_t)q * Cn + ch * 256 + 32 * j + cx] = o[i][jj] * linv[i];
        }
    }
}

// ---- final: out[b,c,l] = mvn(content) + O[b,l,c] (LDS transpose) ----
__global__ __launch_bounds__(256) void final_kernel(const float* __restrict__ content,
                                                    const float* __restrict__ mean_c,
                                                    const float* __restrict__ rstd_c,
                                                    const float* __restrict__ O,
                                                    float* __restrict__ out) {
    __shared__ float t[32][33];
    int b = blockIdx.z, c0 = blockIdx.y * 32, l0 = blockIdx.x * 32;
    int tid = threadIdx.x;
    const size_t bLC = (size_t)b * Ln * Cn;
    const size_t bCL = (size_t)b * Cn * Ln;
#pragma unroll
    for (int p = 0; p < 4; p++) {
        int r = (tid >> 5) + p * 8;     // l row
        int col = tid & 31;             // c col
        t[r][col] = O[bLC + (size_t)(l0 + r) * Cn + c0 + col];
    }
    __syncthreads();
#pragma unroll
    for (int p = 0; p < 4; p++) {
        int cr = (tid >> 5) + p * 8;    // c row
        int lcol = tid & 31;            // l col
        int cg = c0 + cr;
        size_t idx = bCL + (size_t)cg * Ln + l0 + lcol;
        out[idx] = (content[idx] - mean_c[b * Cn + cg]) * rstd_c[b * Cn + cg] + t[lcol][cr];
    }
}

extern "C" void kernel_launch(void* const* d_in, const int* in_sizes, int n_in,
                              void* d_out, int out_size, void* d_ws, size_t ws_size,
                              hipStream_t stream) {
    const float* content = (const float*)d_in[0];
    const float* style   = (const float*)d_in[1];
    const float* v_w   = (const float*)d_in[2];
    const float* v_b   = (const float*)d_in[3];
    const float* vsp_w = (const float*)d_in[4];
    const float* vsp_b = (const float*)d_in[5];
    const float* k_w   = (const float*)d_in[6];
    const float* k_b   = (const float*)d_in[7];
    const float* qg_w  = (const float*)d_in[8];
    const float* qg_b  = (const float*)d_in[9];
    const float* g1_w1 = (const float*)d_in[10];
    const float* g1_b1 = (const float*)d_in[11];
    const float* g1_w2 = (const float*)d_in[12];
    const float* g1_b2 = (const float*)d_in[13];
    const float* g2_w1 = (const float*)d_in[14];
    const float* g2_b1 = (const float*)d_in[15];
    const float* g2_w2 = (const float*)d_in[16];
    const float* g2_b2 = (const float*)d_in[17];

    float* ws = (float*)d_ws;
    float* Vt     = ws + OFF_VT;
    float* Qt     = ws + OFF_QT;
    float* mean_s = ws + OFF_MEANS;
    float* rstd_s = ws + OFF_RSTDS;
    float* mean_c = ws + OFF_MEANC;
    float* rstd_c = ws + OFF_RSTDC;
    float* kp     = ws + OFF_KP;
    float* gsv    = ws + OFF_GSV;
    float* h1     = ws + OFF_H1;
    float* h2     = ws + OFF_H2;
    float* gamma  = ws + OFF_GAMMA;
    float* beta   = ws + OFF_BETA;
    float* Kd     = (float*)d_out;   // K lives in d_out until the final kernel
    float* outF   = (float*)d_out;

    // 1) stats
    stats_kernel<<<dim3(Bn * Cn), 256, 0, stream>>>(style, mean_s, rstd_s);
    stats_kernel<<<dim3(Bn * Cn), 256, 0, stream>>>(content, mean_c, rstd_c);

    // 2) convs: V (transposed), K (into d_out), Q_guide (normalized content, transposed)
    dim3 cgrid(Ln / 64, Cn / 64, Bn);
    conv_kernel<false, true><<<cgrid, 256, 0, stream>>>(style, v_w, v_b, nullptr, nullptr, Vt);
    conv_kernel<false, false><<<cgrid, 256, 0, stream>>>(style, k_w, k_b, nullptr, nullptr, Kd);
    conv_kernel<true, true><<<cgrid, 256, 0, stream>>>(content, qg_w, qg_b, mean_c, rstd_c, Qt);

    // 3) key_pool + softmax -> style weights
    keypool_kernel<<<dim3(Ln / 256, Bn), 256, 0, stream>>>(style, vsp_w, vsp_b, mean_s, rstd_s, kp);
    softmax_kp_kernel<<<dim3(Bn), 1024, 0, stream>>>(kp);

    // 4) gsv + MLPs -> gamma, beta
    gsv_kernel<<<dim3(Cn / 32, Bn), 256, 0, stream>>>(Vt, kp, gsv);
    mlp_hidden_kernel<<<dim3(Bn * Cn / 256), 256, 0, stream>>>(gsv, g1_w1, g1_b1, g2_w1, g2_b1, h1, h2);
    mlp_out_kernel<<<dim3(Bn * Cn / 256), 256, 0, stream>>>(h1, h2, g1_w2, g1_b2, g2_w2, g2_b2, gamma, beta);

    // 5) flash attention (O overwrites Qt)
    flash_kernel<<<dim3(Ln / 32, Bn), 256, 0, stream>>>(Qt, Kd, Vt, gamma, beta);

    // 6) final: mvn(content) + O^T  (overwrites K in d_out)
    final_kernel<<<dim3(Ln / 32, Cn / 32, Bn), 256, 0, stream>>>(content, mean_c, rstd_c, Qt, outF);
}

// Round 4
// 1204.038 us; speedup vs baseline: 3.3160x; 3.3160x over previous
//
#include <hip/hip_runtime.h>
#include <math.h>

typedef __bf16 bf16_t;
typedef __attribute__((ext_vector_type(8))) __bf16 bf16x8;
typedef __attribute__((ext_vector_type(4))) __bf16 bf16x4;
typedef __attribute__((ext_vector_type(4))) float f32x4;

namespace {
constexpr int Bn = 4;
constexpr int Cn = 512;
constexpr int Ln = 4096;   // 64*64
constexpr float kEps = 1e-5f;
constexpr size_t NQK = (size_t)Bn * Ln * Cn;   // 8388608

// float-region offsets (in floats), placed after 5*NQK bf16 elements
constexpr size_t OFF_MEANS = 0;
constexpr size_t OFF_RSTDS = 2048;
constexpr size_t OFF_MEANC = 4096;
constexpr size_t OFF_RSTDC = 6144;
constexpr size_t OFF_KP    = 8192;              // B*Ln = 16384
constexpr size_t OFF_GSV   = OFF_KP + 16384;
constexpr size_t OFF_H1    = OFF_GSV + 2048;
constexpr size_t OFF_H2    = OFF_H1 + 2048;
constexpr size_t OFF_GAMMA = OFF_H2 + 2048;
constexpr size_t OFF_BETA  = OFF_GAMMA + 2048;
} // namespace

__device__ inline f32x4 mfma16(bf16x8 a, bf16x8 b, f32x4 c) {
    return __builtin_amdgcn_mfma_f32_16x16x32_bf16(a, b, c, 0, 0, 0);
}

union Frag8 { bf16x8 v8; bf16x4 v4[2]; };

// ---- per-(b,c) mean & rstd over L, ddof=1 ----
__global__ __launch_bounds__(256) void stats_kernel(const float* __restrict__ x,
                                                    float* __restrict__ mean,
                                                    float* __restrict__ rstd) {
    int bc = blockIdx.x;
    const float* row = x + (size_t)bc * Ln;
    float s1 = 0.f, s2 = 0.f;
    for (int i = threadIdx.x; i < Ln; i += 256) {
        float v = row[i];
        s1 += v; s2 += v * v;
    }
    for (int off = 32; off; off >>= 1) {
        s1 += __shfl_down(s1, off);
        s2 += __shfl_down(s2, off);
    }
    __shared__ float a1[4], a2[4];
    int wid = threadIdx.x >> 6;
    if ((threadIdx.x & 63) == 0) { a1[wid] = s1; a2[wid] = s2; }
    __syncthreads();
    if (threadIdx.x == 0) {
        s1 = a1[0] + a1[1] + a1[2] + a1[3];
        s2 = a2[0] + a2[1] + a2[2] + a2[3];
        float m = s1 / Ln;
        float var = (s2 - m * s1) / (Ln - 1);
        mean[bc] = m;
        rstd[bc] = 1.0f / sqrtf(var + kEps);
    }
}

// ---- conv1x1 as tiled GEMM with bf16 epilogues ----
// MODE 0: V  -> out0 bf16 [B][C][L]
// MODE 1: K  -> out0/out1 bf16 hi/lo [B][L][C]   (K^T)
// MODE 2: Q  -> normalized input, gamma/beta fused, split hi/lo [B][L][C]
template <int MODE>
__global__ __launch_bounds__(256) void conv_kernel(const float* __restrict__ X,
                                                   const float* __restrict__ W,
                                                   const float* __restrict__ bias,
                                                   const float* __restrict__ mean,
                                                   const float* __restrict__ rstd,
                                                   const float* __restrict__ gma,
                                                   const float* __restrict__ bta,
                                                   bf16_t* __restrict__ out0,
                                                   bf16_t* __restrict__ out1) {
    int b = blockIdx.z;
    int o0 = blockIdx.y * 64;
    int l0 = blockIdx.x * 64;
    int tid = threadIdx.x;
    const size_t bCL = (size_t)b * Cn * Ln;
    const size_t bLC = (size_t)b * Ln * Cn;

    __shared__ float Ws[64][17];
    __shared__ float Xs[16][68];

    int ty = tid >> 4;
    int tx = tid & 15;

    float acc[4][4];
#pragma unroll
    for (int i = 0; i < 4; i++)
#pragma unroll
        for (int j = 0; j < 4; j++) acc[i][j] = 0.f;

    for (int cc = 0; cc < Cn; cc += 16) {
        {
            int o = tid >> 2, kf = (tid & 3) * 4;
            float4 w4 = *(const float4*)(W + (size_t)(o0 + o) * Cn + cc + kf);
            Ws[o][kf + 0] = w4.x; Ws[o][kf + 1] = w4.y;
            Ws[o][kf + 2] = w4.z; Ws[o][kf + 3] = w4.w;
        }
        {
            int k = tid >> 4, lf = (tid & 15) * 4;
            float4 x4 = *(const float4*)(X + bCL + (size_t)(cc + k) * Ln + l0 + lf);
            if constexpr (MODE == 2) {
                float mm = mean[b * Cn + cc + k];
                float rr = rstd[b * Cn + cc + k];
                x4.x = (x4.x - mm) * rr; x4.y = (x4.y - mm) * rr;
                x4.z = (x4.z - mm) * rr; x4.w = (x4.w - mm) * rr;
            }
            Xs[k][lf + 0] = x4.x; Xs[k][lf + 1] = x4.y;
            Xs[k][lf + 2] = x4.z; Xs[k][lf + 3] = x4.w;
        }
        __syncthreads();
#pragma unroll
        for (int k = 0; k < 16; k++) {
            float a[4], x[4];
#pragma unroll
            for (int i = 0; i < 4; i++) a[i] = Ws[4 * ty + i][k];
#pragma unroll
            for (int j = 0; j < 4; j++) x[j] = Xs[k][tx + 16 * j];
#pragma unroll
            for (int i = 0; i < 4; i++)
#pragma unroll
                for (int j = 0; j < 4; j++) acc[i][j] += a[i] * x[j];
        }
        __syncthreads();
    }
#pragma unroll
    for (int i = 0; i < 4; i++) {
        int o = o0 + 4 * ty + i;
        float bv = bias[o];
        float gv = 0.f, bt = 0.f;
        if constexpr (MODE == 2) { gv = gma[b * Cn + o]; bt = bta[b * Cn + o]; }
#pragma unroll
        for (int j = 0; j < 4; j++) {
            int l = l0 + tx + 16 * j;
            float v = acc[i][j] + bv;
            if constexpr (MODE == 0) {
                out0[bCL + (size_t)o * Ln + l] = (bf16_t)v;
            } else {
                if constexpr (MODE == 2) v = v * (1.f + gv) + bt;
                bf16_t h = (bf16_t)v;
                bf16_t lo = (bf16_t)(v - (float)h);
                out0[bLC + (size_t)l * Cn + o] = h;
                out1[bLC + (size_t)l * Cn + o] = lo;
            }
        }
    }
}

// ---- key_pool[b,l] = sum_c vsp_w[c]*mvn(style)[b,c,l] + vsp_b ----
__global__ __launch_bounds__(256) void keypool_kernel(const float* __restrict__ style,
                                                      const float* __restrict__ vsp_w,
                                                      const float* __restrict__ vsp_b,
                                                      const float* __restrict__ mean_s,
                                                      const float* __restrict__ rstd_s,
                                                      float* __restrict__ kp) {
    int b = blockIdx.y;
    int l = blockIdx.x * 256 + threadIdx.x;
    const size_t bCL = (size_t)b * Cn * Ln;
    float acc = 0.f;
    for (int c = 0; c < Cn; c++) {
        float v = style[bCL + (size_t)c * Ln + l];
        acc += vsp_w[c] * (v - mean_s[b * Cn + c]) * rstd_s[b * Cn + c];
    }
    kp[b * Ln + l] = acc + vsp_b[0];
}

// ---- softmax over L per b, in place ----
__global__ __launch_bounds__(1024) void softmax_kp_kernel(float* __restrict__ kp) {
    int b = blockIdx.x;
    float* p = kp + (size_t)b * Ln;
    int tid = threadIdx.x;
    float v[4];
    float m = -3e38f;
#pragma unroll
    for (int j = 0; j < 4; j++) { v[j] = p[tid + 1024 * j]; m = fmaxf(m, v[j]); }
    __shared__ float red[16];
    for (int off = 32; off; off >>= 1) m = fmaxf(m, __shfl_down(m, off));
    if ((tid & 63) == 0) red[tid >> 6] = m;
    __syncthreads();
    if (tid == 0) {
        float mm = red[0];
        for (int i = 1; i < 16; i++) mm = fmaxf(mm, red[i]);
        red[0] = mm;
    }
    __syncthreads();
    m = red[0];
    __syncthreads();
    float e[4]; float s = 0.f;
#pragma unroll
    for (int j = 0; j < 4; j++) { e[j] = __expf(v[j] - m); s += e[j]; }
    for (int off = 32; off; off >>= 1) s += __shfl_down(s, off);
    if ((tid & 63) == 0) red[tid >> 6] = s;
    __syncthreads();
    if (tid == 0) {
        float ss = 0.f;
        for (int i = 0; i < 16; i++) ss += red[i];
        red[0] = ss;
    }
    __syncthreads();
    float inv = 1.0f / red[0];
#pragma unroll
    for (int j = 0; j < 4; j++) p[tid + 1024 * j] = e[j] * inv;
}

// ---- gsv[b,c] = sum_l Vb[b,c,l]*w[b,l]  (Vb bf16 [B][C][L]) ----
__global__ __launch_bounds__(256) void gsv_kernel(const bf16_t* __restrict__ Vb,
                                                  const float* __restrict__ w,
                                                  float* __restrict__ gsv) {
    int c = blockIdx.x, b = blockIdx.y;
    int tid = threadIdx.x;
    const bf16_t* vp = Vb + ((size_t)b * Cn + c) * Ln;
    const float* wp = w + (size_t)b * Ln;
    float acc = 0.f;
    for (int base = tid * 8; base < Ln; base += 2048) {
        bf16x8 v = *(const bf16x8*)(vp + base);
        float4 w0 = *(const float4*)(wp + base);
        float4 w1 = *(const float4*)(wp + base + 4);
        acc += (float)v[0] * w0.x + (float)v[1] * w0.y + (float)v[2] * w0.z + (float)v[3] * w0.w;
        acc += (float)v[4] * w1.x + (float)v[5] * w1.y + (float)v[6] * w1.z + (float)v[7] * w1.w;
    }
    for (int off = 32; off; off >>= 1) acc += __shfl_down(acc, off);
    __shared__ float red[4];
    if ((tid & 63) == 0) red[tid >> 6] = acc;
    __syncthreads();
    if (tid == 0) gsv[(size_t)b * Cn + c] = red[0] + red[1] + red[2] + red[3];
}

// ---- MLP stage 1 ----
__global__ __launch_bounds__(256) void mlp_hidden_kernel(const float* __restrict__ gsv,
                                                         const float* __restrict__ w1a, const float* __restrict__ b1a,
                                                         const float* __restrict__ w1b, const float* __restrict__ b1b,
                                                         float* __restrict__ h1, float* __restrict__ h2) {
    int idx = blockIdx.x * 256 + threadIdx.x;
    int b = idx / Cn, c = idx % Cn;
    float a1 = b1a[c], a2 = b1b[c];
    for (int k = 0; k < Cn; k++) {
        float g = gsv[b * Cn + k];
        a1 += w1a[(size_t)c * Cn + k] * g;
        a2 += w1b[(size_t)c * Cn + k] * g;
    }
    h1[idx] = fmaxf(a1, 0.f);
    h2[idx] = fmaxf(a2, 0.f);
}

// ---- MLP stage 2 ----
__global__ __launch_bounds__(256) void mlp_out_kernel(const float* __restrict__ h1, const float* __restrict__ h2,
                                                      const float* __restrict__ w2a, const float* __restrict__ b2a,
                                                      const float* __restrict__ w2b, const float* __restrict__ b2b,
                                                      float* __restrict__ gamma, float* __restrict__ beta) {
    int idx = blockIdx.x * 256 + threadIdx.x;
    int b = idx / Cn, c = idx % Cn;
    float a1 = b2a[c], a2 = b2b[c];
    for (int k = 0; k < Cn; k++) {
        a1 += w2a[(size_t)c * Cn + k] * h1[b * Cn + k];
        a2 += w2b[(size_t)c * Cn + k] * h2[b * Cn + k];
    }
    gamma[idx] = a1;
    beta[idx] = a2;
}

// ---- MFMA flash attention: BQ=64, BK=64, 4 waves, split-bf16 energy ----
// Writes O^T (= [B][C][L]) directly into d_out.
__global__ __launch_bounds__(256, 1) void flash_kernel(
    const bf16_t* __restrict__ Qhi, const bf16_t* __restrict__ Qlo,
    const bf16_t* __restrict__ Khi, const bf16_t* __restrict__ Klo,
    const bf16_t* __restrict__ Vb, float* __restrict__ Ot) {
    const int b = blockIdx.y;
    const int q0 = blockIdx.x * 64;
    const int tid = threadIdx.x;
    const int lane = tid & 63;
    const int wid = tid >> 6;
    const int wm = wid & 1, wn = wid >> 1;
    const int lg = lane >> 4, li = lane & 15;

    __shared__ __align__(16) unsigned short qhi_s[64 * 512];   // 64KB
    __shared__ __align__(16) unsigned short qlo_s[64 * 512];   // 64KB
    __shared__ __align__(16) unsigned short kv_s[2 * 64 * 64]; // 16KB (K hi|lo  /  V 128x64)
    __shared__ __align__(16) unsigned short pb_s[64 * 64];     // 8KB
    __shared__ float smx[2][64];
    __shared__ float sml[2][64];

    // ---- stage Q tile (hi & lo), XOR-swizzled ----
    const size_t qbase = ((size_t)b * Ln + q0) * Cn;
#pragma unroll
    for (int p = 0; p < 16; p++) {
        int idx = p * 256 + tid;
        int row = idx >> 6;
        int c = (idx & 63) * 8;
        unsigned off = (unsigned)((row * 512 + c) * 2) ^ (unsigned)((row & 7) << 4);
        *(bf16x8*)((char*)qhi_s + off) = *(const bf16x8*)(Qhi + qbase + (size_t)row * Cn + c);
        *(bf16x8*)((char*)qlo_s + off) = *(const bf16x8*)(Qlo + qbase + (size_t)row * Cn + c);
    }

    f32x4 o[2][16];
#pragma unroll
    for (int m = 0; m < 2; m++)
#pragma unroll
        for (int j = 0; j < 16; j++) o[m][j] = (f32x4){0.f, 0.f, 0.f, 0.f};
    float m_run[2][4], l_run[2][4];
#pragma unroll
    for (int m = 0; m < 2; m++)
#pragma unroll
        for (int r = 0; r < 4; r++) { m_run[m][r] = -1e30f; l_run[m][r] = 0.f; }

    const size_t kbase = (size_t)b * Ln * Cn;
    const size_t vbase = (size_t)b * Cn * Ln;

    // per-thread staging coordinates
    int kkey[2], kseg[2];
#pragma unroll
    for (int p = 0; p < 2; p++) { int idx = p * 256 + tid; kkey[p] = idx >> 3; kseg[p] = (idx & 7) * 8; }
    int vcl[4], vseg[4];
#pragma unroll
    for (int p = 0; p < 4; p++) { int idx = p * 256 + tid; vcl[p] = idx >> 3; vseg[p] = (idx & 7) * 8; }

    __syncthreads();

    for (int kt = 0; kt < Ln; kt += 64) {
        // ================= energy =================
        f32x4 e[2][2];
#pragma unroll
        for (int m = 0; m < 2; m++)
#pragma unroll
            for (int n = 0; n < 2; n++) e[m][n] = (f32x4){0.f, 0.f, 0.f, 0.f};

        bf16x8 kreg[2][2];
#pragma unroll
        for (int p = 0; p < 2; p++) {
            const size_t gi = kbase + (size_t)(kt + kkey[p]) * Cn + kseg[p];
            kreg[p][0] = *(const bf16x8*)(Khi + gi);
            kreg[p][1] = *(const bf16x8*)(Klo + gi);
        }
        for (int cs = 0; cs < 8; cs++) {
            const int cc = cs * 64;
            __syncthreads();   // prior readers of kv_s done
#pragma unroll
            for (int p = 0; p < 2; p++) {
                unsigned off = (unsigned)((kkey[p] * 64 + kseg[p]) * 2) ^ (unsigned)((kkey[p] & 7) << 4);
                *(bf16x8*)((char*)kv_s + off) = kreg[p][0];
                *(bf16x8*)((char*)kv_s + 8192 + off) = kreg[p][1];
            }
            if (cs < 7) {
#pragma unroll
                for (int p = 0; p < 2; p++) {
                    const size_t gi = kbase + (size_t)(kt + kkey[p]) * Cn + (cc + 64) + kseg[p];
                    kreg[p][0] = *(const bf16x8*)(Khi + gi);
                    kreg[p][1] = *(const bf16x8*)(Klo + gi);
                }
            }
            __syncthreads();   // staged K visible
#pragma unroll
            for (int k2 = 0; k2 < 2; k2++) {
                Frag8 ah[2], al[2];
#pragma unroll
                for (int m = 0; m < 2; m++) {
                    int row = wm * 32 + m * 16 + li;
                    int c = cc + k2 * 32 + lg * 4;
                    unsigned swz = (unsigned)((row & 7) << 4);
                    unsigned off0 = (unsigned)((row * 512 + c) * 2) ^ swz;
                    unsigned off1 = (unsigned)((row * 512 + c + 16) * 2) ^ swz;
                    ah[m].v4[0] = *(const bf16x4*)((char*)qhi_s + off0);
                    ah[m].v4[1] = *(const bf16x4*)((char*)qhi_s + off1);
                    al[m].v4[0] = *(const bf16x4*)((char*)qlo_s + off0);
                    al[m].v4[1] = *(const bf16x4*)((char*)qlo_s + off1);
                }
                Frag8 bh[2], bl[2];
#pragma unroll
                for (int n = 0; n < 2; n++) {
                    int key = wn * 32 + n * 16 + li;
                    int c = k2 * 32 + lg * 4;
                    unsigned swz = (unsigned)((key & 7) << 4);
                    unsigned off0 = (unsigned)((key * 64 + c) * 2) ^ swz;
                    unsigned off1 = (unsigned)((key * 64 + c + 16) * 2) ^ swz;
                    bh[n].v4[0] = *(const bf16x4*)((char*)kv_s + off0);
                    bh[n].v4[1] = *(const bf16x4*)((char*)kv_s + off1);
                    bl[n].v4[0] = *(const bf16x4*)((char*)kv_s + 8192 + off0);
                    bl[n].v4[1] = *(const bf16x4*)((char*)kv_s + 8192 + off1);
                }
#pragma unroll
                for (int m = 0; m < 2; m++)
#pragma unroll
                    for (int n = 0; n < 2; n++) {
                        e[m][n] = mfma16(ah[m].v8, bh[n].v8, e[m][n]);
                        e[m][n] = mfma16(ah[m].v8, bl[n].v8, e[m][n]);
                        e[m][n] = mfma16(al[m].v8, bh[n].v8, e[m][n]);
                    }
            }
        }

        // ================= online softmax =================
        float tmax[2][4];
#pragma unroll
        for (int m = 0; m < 2; m++)
#pragma unroll
            for (int r = 0; r < 4; r++) tmax[m][r] = fmaxf(e[m][0][r], e[m][1][r]);
#pragma unroll
        for (int d = 1; d < 16; d <<= 1)
#pragma unroll
            for (int m = 0; m < 2; m++)
#pragma unroll
                for (int r = 0; r < 4; r++) tmax[m][r] = fmaxf(tmax[m][r], __shfl_xor(tmax[m][r], d));
        if (li == 0) {
#pragma unroll
            for (int m = 0; m < 2; m++)
#pragma unroll
                for (int r = 0; r < 4; r++) smx[wn][wm * 32 + m * 16 + lg * 4 + r] = tmax[m][r];
        }
        __syncthreads();
        float scv[2][4];
#pragma unroll
        for (int m = 0; m < 2; m++)
#pragma unroll
            for (int r = 0; r < 4; r++) {
                int row = wm * 32 + m * 16 + lg * 4 + r;
                float tm = fmaxf(smx[0][row], smx[1][row]);
                float mnew = fmaxf(m_run[m][r], tm);
                scv[m][r] = __expf(m_run[m][r] - mnew);
                m_run[m][r] = mnew;
            }
        float pv[2][2][4];
        float rsum[2][4];
#pragma unroll
        for (int m = 0; m < 2; m++)
#pragma unroll
            for (int r = 0; r < 4; r++) rsum[m][r] = 0.f;
#pragma unroll
        for (int m = 0; m < 2; m++)
#pragma unroll
            for (int n = 0; n < 2; n++)
#pragma unroll
                for (int r = 0; r < 4; r++) {
                    float pe = __expf(e[m][n][r] - m_run[m][r]);
                    pv[m][n][r] = pe;
                    rsum[m][r] += pe;
                }
#pragma unroll
        for (int d = 1; d < 16; d <<= 1)
#pragma unroll
            for (int m = 0; m < 2; m++)
#pragma unroll
                for (int r = 0; r < 4; r++) rsum[m][r] += __shfl_xor(rsum[m][r], d);
        if (li == 0) {
#pragma unroll
            for (int m = 0; m < 2; m++)
#pragma unroll
                for (int r = 0; r < 4; r++) sml[wn][wm * 32 + m * 16 + lg * 4 + r] = rsum[m][r];
        }
        // write P (bf16) to LDS, swizzled
#pragma unroll
        for (int m = 0; m < 2; m++)
#pragma unroll
            for (int n = 0; n < 2; n++)
#pragma unroll
                for (int r = 0; r < 4; r++) {
                    int ql = wm * 32 + m * 16 + lg * 4 + r;
                    int kl = wn * 32 + n * 16 + li;
                    unsigned boff = (unsigned)((ql * 64 + kl) * 2) ^ (unsigned)((ql & 7) << 4);
                    *(bf16_t*)((char*)pb_s + boff) = (bf16_t)pv[m][n][r];
                }
        // rescale O
#pragma unroll
        for (int m = 0; m < 2; m++)
#pragma unroll
            for (int j = 0; j < 16; j++)
#pragma unroll
                for (int r = 0; r < 4; r++) o[m][j][r] *= scv[m][r];
        __syncthreads();   // sml + pb ready; kv_s free for V
#pragma unroll
        for (int m = 0; m < 2; m++)
#pragma unroll
            for (int r = 0; r < 4; r++) {
                int row = wm * 32 + m * 16 + lg * 4 + r;
                l_run[m][r] = l_run[m][r] * scv[m][r] + sml[0][row] + sml[1][row];
            }

        // ================= PV =================
        Frag8 pa[2][2];
#pragma unroll
        for (int m = 0; m < 2; m++)
#pragma unroll
            for (int k2 = 0; k2 < 2; k2++) {
                int ql = wm * 32 + m * 16 + li;
                int kp = k2 * 32 + lg * 4;
                unsigned swz = (unsigned)((ql & 7) << 4);
                pa[m][k2].v4[0] = *(const bf16x4*)((char*)pb_s + ((unsigned)((ql * 64 + kp) * 2) ^ swz));
                pa[m][k2].v4[1] = *(const bf16x4*)((char*)pb_s + ((unsigned)((ql * 64 + kp + 16) * 2) ^ swz));
            }
        bf16x8 vreg[4];
#pragma unroll
        for (int p = 0; p < 4; p++)
            vreg[p] = *(const bf16x8*)(Vb + vbase + (size_t)vcl[p] * Ln + kt + vseg[p]);
        for (int vs = 0; vs < 4; vs++) {
#pragma unroll
            for (int p = 0; p < 4; p++) {
                unsigned off = (unsigned)((vcl[p] * 64 + vseg[p]) * 2) ^ (unsigned)((vcl[p] & 7) << 4);
                *(bf16x8*)((char*)kv_s + off) = vreg[p];
            }
            if (vs < 3) {
#pragma unroll
                for (int p = 0; p < 4; p++)
                    vreg[p] = *(const bf16x8*)(Vb + vbase + (size_t)((vs + 1) * 128 + vcl[p]) * Ln + kt + vseg[p]);
            }
            __syncthreads();   // V chunk visible
#pragma unroll
            for (int jj = 0; jj < 4; jj++) {
                int cl = (wn + 2 * jj) * 16 + li;
                unsigned swz = (unsigned)((cl & 7) << 4);
#pragma unroll
                for (int k2 = 0; k2 < 2; k2++) {
                    int key = k2 * 32 + lg * 4;
                    Frag8 bv;
                    bv.v4[0] = *(const bf16x4*)((char*)kv_s + ((unsigned)((cl * 64 + key) * 2) ^ swz));
                    bv.v4[1] = *(const bf16x4*)((char*)kv_s + ((unsigned)((cl * 64 + key + 16) * 2) ^ swz));
#pragma unroll
                    for (int m = 0; m < 2; m++)
                        o[m][vs * 4 + jj] = mfma16(pa[m][k2].v8, bv.v8, o[m][vs * 4 + jj]);
                }
            }
            __syncthreads();   // MFMA reads done before next overwrite
        }
    }

    // ================= epilogue: O^T -> d_out [B][C][L] =================
#pragma unroll
    for (int m = 0; m < 2; m++)
#pragma unroll
        for (int r = 0; r < 4; r++) l_run[m][r] = 1.f / l_run[m][r];
#pragma unroll
    for (int m = 0; m < 2; m++)
#pragma unroll
        for (int j = 0; j < 16; j++) {
            int ct = (j >> 2) * 8 + wn + 2 * (j & 3);
            int c = ct * 16 + li;
#pragma unroll
            for (int r = 0; r < 4; r++) {
                int qg = q0 + wm * 32 + m * 16 + lg * 4 + r;
                Ot[vbase + (size_t)c * Ln + qg] = o[m][j][r] * l_run[m][r];
            }
        }
}

// ---- final: out[b,c,l] = mvn(content)[b,c,l] + out[b,c,l]  (in place) ----
__global__ __launch_bounds__(256) void final_kernel(const float* __restrict__ content,
                                                    const float* __restrict__ mean_c,
                                                    const float* __restrict__ rstd_c,
                                                    float* __restrict__ out) {
    size_t gid = (size_t)blockIdx.x * 256 + threadIdx.x;   // float4 index
    size_t linear = gid * 4;
    int ch = (int)(linear / Ln);   // b*Cn + c
    float m = mean_c[ch], rs = rstd_c[ch];
    float4 cv = *(const float4*)(content + linear);
    float4 ov = *(const float4*)(out + linear);
    ov.x += (cv.x - m) * rs;
    ov.y += (cv.y - m) * rs;
    ov.z += (cv.z - m) * rs;
    ov.w += (cv.w - m) * rs;
    *(float4*)(out + linear) = ov;
}

extern "C" void kernel_launch(void* const* d_in, const int* in_sizes, int n_in,
                              void* d_out, int out_size, void* d_ws, size_t ws_size,
                              hipStream_t stream) {
    const float* content = (const float*)d_in[0];
    const float* style   = (const float*)d_in[1];
    const float* v_w   = (const float*)d_in[2];
    const float* v_b   = (const float*)d_in[3];
    const float* vsp_w = (const float*)d_in[4];
    const float* vsp_b = (const float*)d_in[5];
    const float* k_w   = (const float*)d_in[6];
    const float* k_b   = (const float*)d_in[7];
    const float* qg_w  = (const float*)d_in[8];
    const float* qg_b  = (const float*)d_in[9];
    const float* g1_w1 = (const float*)d_in[10];
    const float* g1_b1 = (const float*)d_in[11];
    const float* g1_w2 = (const float*)d_in[12];
    const float* g1_b2 = (const float*)d_in[13];
    const float* g2_w1 = (const float*)d_in[14];
    const float* g2_b1 = (const float*)d_in[15];
    const float* g2_w2 = (const float*)d_in[16];
    const float* g2_b2 = (const float*)d_in[17];

    bf16_t* wsb = (bf16_t*)d_ws;
    bf16_t* Qhi = wsb;
    bf16_t* Qlo = wsb + NQK;
    bf16_t* Khi = wsb + 2 * NQK;
    bf16_t* Klo = wsb + 3 * NQK;
    bf16_t* Vb  = wsb + 4 * NQK;
    float* wsf = (float*)(wsb + 5 * NQK);
    float* mean_s = wsf + OFF_MEANS;
    float* rstd_s = wsf + OFF_RSTDS;
    float* mean_c = wsf + OFF_MEANC;
    float* rstd_c = wsf + OFF_RSTDC;
    float* kp     = wsf + OFF_KP;
    float* gsv    = wsf + OFF_GSV;
    float* h1     = wsf + OFF_H1;
    float* h2     = wsf + OFF_H2;
    float* gamma  = wsf + OFF_GAMMA;
    float* beta   = wsf + OFF_BETA;
    float* outF   = (float*)d_out;

    // 1) stats
    stats_kernel<<<dim3(Bn * Cn), 256, 0, stream>>>(style, mean_s, rstd_s);
    stats_kernel<<<dim3(Bn * Cn), 256, 0, stream>>>(content, mean_c, rstd_c);

    dim3 cgrid(Ln / 64, Cn / 64, Bn);
    // 2) V conv -> bf16 [B][C][L]
    conv_kernel<0><<<cgrid, 256, 0, stream>>>(style, v_w, v_b, nullptr, nullptr, nullptr, nullptr, Vb, nullptr);

    // 3) key_pool + softmax
    keypool_kernel<<<dim3(Ln / 256, Bn), 256, 0, stream>>>(style, vsp_w, vsp_b, mean_s, rstd_s, kp);
    softmax_kp_kernel<<<dim3(Bn), 1024, 0, stream>>>(kp);

    // 4) gsv + MLPs -> gamma, beta
    gsv_kernel<<<dim3(Cn, Bn), 256, 0, stream>>>(Vb, kp, gsv);
    mlp_hidden_kernel<<<dim3(Bn * Cn / 256), 256, 0, stream>>>(gsv, g1_w1, g1_b1, g2_w1, g2_b1, h1, h2);
    mlp_out_kernel<<<dim3(Bn * Cn / 256), 256, 0, stream>>>(h1, h2, g1_w2, g1_b2, g2_w2, g2_b2, gamma, beta);

    // 5) K^T and Qhat (split bf16)
    conv_kernel<1><<<cgrid, 256, 0, stream>>>(style, k_w, k_b, nullptr, nullptr, nullptr, nullptr, Khi, Klo);
    conv_kernel<2><<<cgrid, 256, 0, stream>>>(content, qg_w, qg_b, mean_c, rstd_c, gamma, beta, Qhi, Qlo);

    // 6) flash attention -> O^T into d_out
    flash_kernel<<<dim3(Ln / 64, Bn), 256, 0, stream>>>(Qhi, Qlo, Khi, Klo, Vb, outF);

    // 7) final: add mvn(content) in place
    final_kernel<<<dim3((Bn * Cn * (Ln / 4)) / 256), 256, 0, stream>>>(content, mean_c, rstd_c, outF);
}

// Round 5
// 932.493 us; speedup vs baseline: 4.2817x; 1.2912x over previous
//
#include <hip/hip_runtime.h>
#include <math.h>

typedef __bf16 bf16_t;
typedef __attribute__((ext_vector_type(8))) __bf16 bf16x8;
typedef __attribute__((ext_vector_type(4))) __bf16 bf16x4;
typedef __attribute__((ext_vector_type(4))) float f32x4;

namespace {
constexpr int Bn = 4;
constexpr int Cn = 512;
constexpr int Ln = 4096;   // 64*64
constexpr float kEps = 1e-5f;
constexpr size_t NQK = (size_t)Bn * Ln * Cn;   // 8388608
constexpr size_t CC  = (size_t)Cn * Cn;        // 262144

// ---- ws layout: bf16 region ----
constexpr size_t OFF_QHI = 0;
constexpr size_t OFF_QLO = NQK;
constexpr size_t OFF_KHI = 2 * NQK;
constexpr size_t OFF_KLO = 3 * NQK;
constexpr size_t OFF_VB  = 4 * NQK;
constexpr size_t OFF_WSP = 5 * NQK;            // 6 × CC weight splits
constexpr size_t BF16_TOTAL = OFF_WSP + 6 * CC;
// ---- float region (offsets in floats, after bf16 region) ----
constexpr size_t FOFF_MEANS = 0;
constexpr size_t FOFF_RSTDS = 2048;
constexpr size_t FOFF_MEANC = 4096;
constexpr size_t FOFF_RSTDC = 6144;
constexpr size_t FOFF_KP    = 8192;            // B*Ln
constexpr size_t FOFF_GSV   = FOFF_KP + 16384;
constexpr size_t FOFF_H1    = FOFF_GSV + 2048;
constexpr size_t FOFF_H2    = FOFF_H1 + 2048;
constexpr size_t FOFF_GAMMA = FOFF_H2 + 2048;
constexpr size_t FOFF_BETA  = FOFF_GAMMA + 2048;
} // namespace

__device__ inline f32x4 mfma16(bf16x8 a, bf16x8 b, f32x4 c) {
    return __builtin_amdgcn_mfma_f32_16x16x32_bf16(a, b, c, 0, 0, 0);
}

union Frag8 { bf16x8 v8; bf16x4 v4[2]; };

__device__ inline unsigned short bf2u(bf16_t x) {
    union { bf16_t b; unsigned short u; } c; c.b = x; return c.u;
}
__device__ inline bf16_t u2bf(unsigned short x) {
    union { bf16_t b; unsigned short u; } c; c.u = x; return c.b;
}

// ---- per-(b,c) mean & rstd over L, ddof=1 ----
__global__ __launch_bounds__(256) void stats_kernel(const float* __restrict__ x,
                                                    float* __restrict__ mean,
                                                    float* __restrict__ rstd) {
    int bc = blockIdx.x;
    const float* row = x + (size_t)bc * Ln;
    float s1 = 0.f, s2 = 0.f;
    for (int i = threadIdx.x; i < Ln; i += 256) {
        float v = row[i];
        s1 += v; s2 += v * v;
    }
    for (int off = 32; off; off >>= 1) {
        s1 += __shfl_down(s1, off);
        s2 += __shfl_down(s2, off);
    }
    __shared__ float a1[4], a2[4];
    int wid = threadIdx.x >> 6;
    if ((threadIdx.x & 63) == 0) { a1[wid] = s1; a2[wid] = s2; }
    __syncthreads();
    if (threadIdx.x == 0) {
        s1 = a1[0] + a1[1] + a1[2] + a1[3];
        s2 = a2[0] + a2[1] + a2[2] + a2[3];
        float m = s1 / Ln;
        float var = (s2 - m * s1) / (Ln - 1);
        mean[bc] = m;
        rstd[bc] = 1.0f / sqrtf(var + kEps);
    }
}

// ---- split 3 weight matrices into bf16 hi/lo ----
__global__ __launch_bounds__(256) void split_w_kernel(const float* __restrict__ w0,
                                                      const float* __restrict__ w1,
                                                      const float* __restrict__ w2,
                                                      bf16_t* __restrict__ wsp) {
    const float* w = (blockIdx.y == 0) ? w0 : (blockIdx.y == 1) ? w1 : w2;
    bf16_t* hi = wsp + (size_t)blockIdx.y * 2 * CC;
    bf16_t* lo = hi + CC;
    size_t i0 = ((size_t)blockIdx.x * 256 + threadIdx.x) * 8;
    float4 a = *(const float4*)(w + i0);
    float4 b = *(const float4*)(w + i0 + 4);
    float vs[8] = {a.x, a.y, a.z, a.w, b.x, b.y, b.z, b.w};
    bf16x8 hv, lv;
#pragma unroll
    for (int i = 0; i < 8; i++) {
        bf16_t h = (bf16_t)vs[i];
        hv[i] = h;
        lv[i] = (bf16_t)(vs[i] - (float)h);
    }
    *(bf16x8*)(hi + i0) = hv;
    *(bf16x8*)(lo + i0) = lv;
}

// ---- transpose+split: X [B][C][L] fp32 -> XT hi/lo [B][L][C] bf16 (opt. mvn) ----
template <bool MVN>
__global__ __launch_bounds__(256) void split_xt_kernel(const float* __restrict__ x,
                                                       const float* __restrict__ mean,
                                                       const float* __restrict__ rstd,
                                                       bf16_t* __restrict__ hi,
                                                       bf16_t* __restrict__ lo) {
    __shared__ bf16_t th[32][40];
    __shared__ bf16_t tl[32][40];
    int b = blockIdx.z, c0 = blockIdx.y * 32, l0 = blockIdx.x * 32;
    const size_t base = (size_t)b * Cn * Ln;
    int lc = threadIdx.x & 31;
    int cr0 = threadIdx.x >> 5;
#pragma unroll
    for (int p = 0; p < 4; p++) {
        int cr = cr0 + p * 8;
        float v = x[base + (size_t)(c0 + cr) * Ln + l0 + lc];
        if constexpr (MVN) {
            v = (v - mean[b * Cn + c0 + cr]) * rstd[b * Cn + c0 + cr];
        }
        bf16_t h = (bf16_t)v;
        th[lc][cr] = h;
        tl[lc][cr] = (bf16_t)(v - (float)h);
    }
    __syncthreads();
    int tt = threadIdx.x & 127;
    int lrow = tt >> 2;
    int c8 = (tt & 3) * 8;
    if (threadIdx.x < 128) {
        *(bf16x8*)(hi + base + (size_t)(l0 + lrow) * Cn + c0 + c8) = *(bf16x8*)&th[lrow][c8];
    } else {
        *(bf16x8*)(lo + base + (size_t)(l0 + lrow) * Cn + c0 + c8) = *(bf16x8*)&tl[lrow][c8];
    }
}

// ---- conv1x1 as split-bf16 MFMA GEMM: out = W(CxC) @ X(CxL) + bias ----
// A = W hi/lo [C][C] (k-contig rows), B = XT hi/lo [B][L][C] (k-contig rows).
// MODE 0: out0 bf16 [B][C][L]
// MODE 1: out0/out1 bf16 hi/lo [B][L][C]
// MODE 2: MODE1 + v = v*(1+gamma)+beta fused
template <int MODE>
__global__ __launch_bounds__(256, 2) void conv_mfma_kernel(
    const bf16_t* __restrict__ Whi, const bf16_t* __restrict__ Wlo,
    const bf16_t* __restrict__ Xhi, const bf16_t* __restrict__ Xlo,
    const float* __restrict__ bias,
    const float* __restrict__ gma, const float* __restrict__ bta,
    bf16_t* __restrict__ out0, bf16_t* __restrict__ out1) {
    const int b = blockIdx.z;
    const int o0 = blockIdx.y * 128;
    const int l0 = blockIdx.x * 128;
    const int tid = threadIdx.x;
    const int lane = tid & 63, wid = tid >> 6;
    const int wm = wid & 1, wn = wid >> 1;
    const int lg = lane >> 4, li = lane & 15;
    const size_t bLC = (size_t)b * Ln * Cn;

    // 66.6 KB: staging (4 × 16KB tiles) unioned with epilogue uint[128*130]
    __shared__ __align__(16) char smem[133120 / 2 + 66560 - 66560 + 66560];  // 66560 B

    f32x4 acc[4][4];
#pragma unroll
    for (int i = 0; i < 4; i++)
#pragma unroll
        for (int j = 0; j < 4; j++) acc[i][j] = (f32x4){0.f, 0.f, 0.f, 0.f};

    for (int cc = 0; cc < Cn; cc += 64) {
        __syncthreads();
#pragma unroll
        for (int p = 0; p < 4; p++) {
            int idx = p * 256 + tid;          // 0..1023
            int row = idx >> 3;               // 0..127
            int c8 = (idx & 7) * 8;           // 0..56
            unsigned off = (unsigned)((row * 64 + c8) * 2) ^ (unsigned)((row & 7) << 4);
            *(bf16x8*)(smem + off)         = *(const bf16x8*)(Whi + (size_t)(o0 + row) * Cn + cc + c8);
            *(bf16x8*)(smem + 16384 + off) = *(const bf16x8*)(Wlo + (size_t)(o0 + row) * Cn + cc + c8);
            *(bf16x8*)(smem + 32768 + off) = *(const bf16x8*)(Xhi + bLC + (size_t)(l0 + row) * Cn + cc + c8);
            *(bf16x8*)(smem + 49152 + off) = *(const bf16x8*)(Xlo + bLC + (size_t)(l0 + row) * Cn + cc + c8);
        }
        __syncthreads();
#pragma unroll
        for (int k2 = 0; k2 < 2; k2++) {
            Frag8 ah[4], al[4], bh[4], bl[4];
#pragma unroll
            for (int f = 0; f < 4; f++) {
                int row = wm * 64 + f * 16 + li;
                unsigned swz = (unsigned)((row & 7) << 4);
                unsigned ob = (unsigned)((row * 64 + k2 * 32 + lg * 4) * 2);
                ah[f].v4[0] = *(const bf16x4*)(smem + ((ob) ^ swz));
                ah[f].v4[1] = *(const bf16x4*)(smem + ((ob + 32) ^ swz));
                al[f].v4[0] = *(const bf16x4*)(smem + 16384 + ((ob) ^ swz));
                al[f].v4[1] = *(const bf16x4*)(smem + 16384 + ((ob + 32) ^ swz));
            }
#pragma unroll
            for (int f = 0; f < 4; f++) {
                int row = wn * 64 + f * 16 + li;
                unsigned swz = (unsigned)((row & 7) << 4);
                unsigned ob = (unsigned)((row * 64 + k2 * 32 + lg * 4) * 2);
                bh[f].v4[0] = *(const bf16x4*)(smem + 32768 + ((ob) ^ swz));
                bh[f].v4[1] = *(const bf16x4*)(smem + 32768 + ((ob + 32) ^ swz));
                bl[f].v4[0] = *(const bf16x4*)(smem + 49152 + ((ob) ^ swz));
                bl[f].v4[1] = *(const bf16x4*)(smem + 49152 + ((ob + 32) ^ swz));
            }
#pragma unroll
            for (int fm = 0; fm < 4; fm++)
#pragma unroll
                for (int fn = 0; fn < 4; fn++) {
                    acc[fm][fn] = mfma16(ah[fm].v8, bh[fn].v8, acc[fm][fn]);
                    acc[fm][fn] = mfma16(ah[fm].v8, bl[fn].v8, acc[fm][fn]);
                    acc[fm][fn] = mfma16(al[fm].v8, bh[fn].v8, acc[fm][fn]);
                }
        }
    }

    if constexpr (MODE == 0) {
        const size_t bCL = (size_t)b * Cn * Ln;
#pragma unroll
        for (int fm = 0; fm < 4; fm++) {
#pragma unroll
            for (int r = 0; r < 4; r++) {
                int o = o0 + wm * 64 + fm * 16 + lg * 4 + r;
                float bv = bias[o];
#pragma unroll
                for (int fn = 0; fn < 4; fn++) {
                    int l = l0 + wn * 64 + fn * 16 + li;
                    out0[bCL + (size_t)o * Ln + l] = (bf16_t)(acc[fm][fn][r] + bv);
                }
            }
        }
    } else {
        __syncthreads();
        unsigned int* ep = (unsigned int*)smem;
#pragma unroll
        for (int fm = 0; fm < 4; fm++) {
#pragma unroll
            for (int r = 0; r < 4; r++) {
                int orow = wm * 64 + fm * 16 + lg * 4 + r;
                int o = o0 + orow;
                float bv = bias[o];
                float gv = 0.f, btv = 0.f;
                if constexpr (MODE == 2) { gv = gma[b * Cn + o]; btv = bta[b * Cn + o]; }
#pragma unroll
                for (int fn = 0; fn < 4; fn++) {
                    int lrow = wn * 64 + fn * 16 + li;
                    float v = acc[fm][fn][r] + bv;
                    if constexpr (MODE == 2) v = v * (1.f + gv) + btv;
                    bf16_t h = (bf16_t)v;
                    bf16_t l2 = (bf16_t)(v - (float)h);
                    ep[lrow * 130 + orow] = (unsigned int)bf2u(h) | ((unsigned int)bf2u(l2) << 16);
                }
            }
        }
        __syncthreads();
#pragma unroll
        for (int p = 0; p < 8; p++) {
            int idx = p * 256 + tid;       // 0..2047
            int lrow = idx >> 4;           // 0..127
            int c8 = (idx & 15) * 8;       // 0..120
            bf16x8 hv, lv;
#pragma unroll
            for (int u = 0; u < 8; u++) {
                unsigned int w = ep[lrow * 130 + c8 + u];
                hv[u] = u2bf((unsigned short)(w & 0xffffu));
                lv[u] = u2bf((unsigned short)(w >> 16));
            }
            *(bf16x8*)(out0 + bLC + (size_t)(l0 + lrow) * Cn + o0 + c8) = hv;
            *(bf16x8*)(out1 + bLC + (size_t)(l0 + lrow) * Cn + o0 + c8) = lv;
        }
    }
}

// ---- key_pool[b,l] = sum_c vsp_w[c]*mvn(style)[b,c,l] + vsp_b ----
__global__ __launch_bounds__(256) void keypool_kernel(const float* __restrict__ style,
                                                      const float* __restrict__ vsp_w,
                                                      const float* __restrict__ vsp_b,
                                                      const float* __restrict__ mean_s,
                                                      const float* __restrict__ rstd_s,
                                                      float* __restrict__ kp) {
    int b = blockIdx.y;
    int l = blockIdx.x * 256 + threadIdx.x;
    const size_t bCL = (size_t)b * Cn * Ln;
    float acc = 0.f;
    for (int c = 0; c < Cn; c++) {
        float v = style[bCL + (size_t)c * Ln + l];
        acc += vsp_w[c] * (v - mean_s[b * Cn + c]) * rstd_s[b * Cn + c];
    }
    kp[b * Ln + l] = acc + vsp_b[0];
}

// ---- softmax over L per b, in place ----
__global__ __launch_bounds__(1024) void softmax_kp_kernel(float* __restrict__ kp) {
    int b = blockIdx.x;
    float* p = kp + (size_t)b * Ln;
    int tid = threadIdx.x;
    float v[4];
    float m = -3e38f;
#pragma unroll
    for (int j = 0; j < 4; j++) { v[j] = p[tid + 1024 * j]; m = fmaxf(m, v[j]); }
    __shared__ float red[16];
    for (int off = 32; off; off >>= 1) m = fmaxf(m, __shfl_down(m, off));
    if ((tid & 63) == 0) red[tid >> 6] = m;
    __syncthreads();
    if (tid == 0) {
        float mm = red[0];
        for (int i = 1; i < 16; i++) mm = fmaxf(mm, red[i]);
        red[0] = mm;
    }
    __syncthreads();
    m = red[0];
    __syncthreads();
    float e[4]; float s = 0.f;
#pragma unroll
    for (int j = 0; j < 4; j++) { e[j] = __expf(v[j] - m); s += e[j]; }
    for (int off = 32; off; off >>= 1) s += __shfl_down(s, off);
    if ((tid & 63) == 0) red[tid >> 6] = s;
    __syncthreads();
    if (tid == 0) {
        float ss = 0.f;
        for (int i = 0; i < 16; i++) ss += red[i];
        red[0] = ss;
    }
    __syncthreads();
    float inv = 1.0f / red[0];
#pragma unroll
    for (int j = 0; j < 4; j++) p[tid + 1024 * j] = e[j] * inv;
}

// ---- gsv[b,c] = sum_l Vb[b,c,l]*w[b,l] ----
__global__ __launch_bounds__(256) void gsv_kernel(const bf16_t* __restrict__ Vb,
                                                  const float* __restrict__ w,
                                                  float* __restrict__ gsv) {
    int c = blockIdx.x, b = blockIdx.y;
    int tid = threadIdx.x;
    const bf16_t* vp = Vb + ((size_t)b * Cn + c) * Ln;
    const float* wp = w + (size_t)b * Ln;
    float acc = 0.f;
    for (int base = tid * 8; base < Ln; base += 2048) {
        bf16x8 v = *(const bf16x8*)(vp + base);
        float4 w0 = *(const float4*)(wp + base);
        float4 w1 = *(const float4*)(wp + base + 4);
        acc += (float)v[0] * w0.x + (float)v[1] * w0.y + (float)v[2] * w0.z + (float)v[3] * w0.w;
        acc += (float)v[4] * w1.x + (float)v[5] * w1.y + (float)v[6] * w1.z + (float)v[7] * w1.w;
    }
    for (int off = 32; off; off >>= 1) acc += __shfl_down(acc, off);
    __shared__ float red[4];
    if ((tid & 63) == 0) red[tid >> 6] = acc;
    __syncthreads();
    if (tid == 0) gsv[(size_t)b * Cn + c] = red[0] + red[1] + red[2] + red[3];
}

// ---- MLP stage 1 ----
__global__ __launch_bounds__(256) void mlp_hidden_kernel(const float* __restrict__ gsv,
                                                         const float* __restrict__ w1a, const float* __restrict__ b1a,
                                                         const float* __restrict__ w1b, const float* __restrict__ b1b,
                                                         float* __restrict__ h1, float* __restrict__ h2) {
    int idx = blockIdx.x * 256 + threadIdx.x;
    int b = idx / Cn, c = idx % Cn;
    float a1 = b1a[c], a2 = b1b[c];
    for (int k = 0; k < Cn; k++) {
        float g = gsv[b * Cn + k];
        a1 += w1a[(size_t)c * Cn + k] * g;
        a2 += w1b[(size_t)c * Cn + k] * g;
    }
    h1[idx] = fmaxf(a1, 0.f);
    h2[idx] = fmaxf(a2, 0.f);
}

// ---- MLP stage 2 ----
__global__ __launch_bounds__(256) void mlp_out_kernel(const float* __restrict__ h1, const float* __restrict__ h2,
                                                      const float* __restrict__ w2a, const float* __restrict__ b2a,
                                                      const float* __restrict__ w2b, const float* __restrict__ b2b,
                                                      float* __restrict__ gamma, float* __restrict__ beta) {
    int idx = blockIdx.x * 256 + threadIdx.x;
    int b = idx / Cn, c = idx % Cn;
    float a1 = b2a[c], a2 = b2b[c];
    for (int k = 0; k < Cn; k++) {
        a1 += w2a[(size_t)c * Cn + k] * h1[b * Cn + k];
        a2 += w2b[(size_t)c * Cn + k] * h2[b * Cn + k];
    }
    gamma[idx] = a1;
    beta[idx] = a2;
}

// ---- MFMA flash attention: BQ=64, BK=64, 8 waves (2 q-sub x 4 key/c-sub) ----
__global__ __launch_bounds__(512, 1) void flash_kernel(
    const bf16_t* __restrict__ Qhi, const bf16_t* __restrict__ Qlo,
    const bf16_t* __restrict__ Khi, const bf16_t* __restrict__ Klo,
    const bf16_t* __restrict__ Vb, float* __restrict__ Ot) {
    const int b = blockIdx.y;
    const int q0 = blockIdx.x * 64;
    const int tid = threadIdx.x;
    const int lane = tid & 63;
    const int wid = tid >> 6;       // 0..7
    const int wm = wid & 1, wn = wid >> 1;   // wn 0..3
    const int lg = lane >> 4, li = lane & 15;

    __shared__ __align__(16) bf16_t qhi_s[64 * 512];   // 64KB
    __shared__ __align__(16) bf16_t qlo_s[64 * 512];   // 64KB
    __shared__ __align__(16) bf16_t kv_s[2 * 64 * 64]; // 16KB
    __shared__ __align__(16) bf16_t pb_s[64 * 64];     // 8KB
    __shared__ float smx[4][64];
    __shared__ float sml[4][64];

    // ---- stage Q tile (hi & lo), XOR-swizzled ----
    const size_t qbase = ((size_t)b * Ln + q0) * Cn;
#pragma unroll
    for (int p = 0; p < 8; p++) {
        int idx = p * 512 + tid;
        int row = idx >> 6;
        int c = (idx & 63) * 8;
        unsigned off = (unsigned)((row * 512 + c) * 2) ^ (unsigned)((row & 7) << 4);
        *(bf16x8*)((char*)qhi_s + off) = *(const bf16x8*)(Qhi + qbase + (size_t)row * Cn + c);
        *(bf16x8*)((char*)qlo_s + off) = *(const bf16x8*)(Qlo + qbase + (size_t)row * Cn + c);
    }

    f32x4 o[2][8];
#pragma unroll
    for (int m = 0; m < 2; m++)
#pragma unroll
        for (int j = 0; j < 8; j++) o[m][j] = (f32x4){0.f, 0.f, 0.f, 0.f};
    float m_run[2][4], l_run[2][4];
#pragma unroll
    for (int m = 0; m < 2; m++)
#pragma unroll
        for (int r = 0; r < 4; r++) { m_run[m][r] = -1e30f; l_run[m][r] = 0.f; }

    const size_t kbase = (size_t)b * Ln * Cn;
    const size_t vbase = (size_t)b * Cn * Ln;

    const int kkey = tid >> 3, kseg = (tid & 7) * 8;
    int vcl[2], vseg[2];
#pragma unroll
    for (int p = 0; p < 2; p++) { int idx = p * 512 + tid; vcl[p] = idx >> 3; vseg[p] = (idx & 7) * 8; }

    __syncthreads();

    for (int kt = 0; kt < Ln; kt += 64) {
        // ================= energy =================
        f32x4 e[2];
#pragma unroll
        for (int m = 0; m < 2; m++) e[m] = (f32x4){0.f, 0.f, 0.f, 0.f};

        bf16x8 kreg[2];
        kreg[0] = *(const bf16x8*)(Khi + kbase + (size_t)(kt + kkey) * Cn + kseg);
        kreg[1] = *(const bf16x8*)(Klo + kbase + (size_t)(kt + kkey) * Cn + kseg);
        for (int cs = 0; cs < 8; cs++) {
            const int cc = cs * 64;
            __syncthreads();   // prior readers of kv_s done
            {
                unsigned koff = (unsigned)((kkey * 64 + kseg) * 2) ^ (unsigned)((kkey & 7) << 4);
                *(bf16x8*)((char*)kv_s + koff) = kreg[0];
                *(bf16x8*)((char*)kv_s + 8192 + koff) = kreg[1];
            }
            if (cs < 7) {
                kreg[0] = *(const bf16x8*)(Khi + kbase + (size_t)(kt + kkey) * Cn + cc + 64 + kseg);
                kreg[1] = *(const bf16x8*)(Klo + kbase + (size_t)(kt + kkey) * Cn + cc + 64 + kseg);
            }
            __syncthreads();   // staged K visible
#pragma unroll
            for (int k2 = 0; k2 < 2; k2++) {
                Frag8 ah[2], al[2];
#pragma unroll
                for (int m = 0; m < 2; m++) {
                    int row = wm * 32 + m * 16 + li;
                    int c = cc + k2 * 32 + lg * 4;
                    unsigned swz = (unsigned)((row & 7) << 4);
                    unsigned off0 = (unsigned)((row * 512 + c) * 2) ^ swz;
                    unsigned off1 = (unsigned)((row * 512 + c + 16) * 2) ^ swz;
                    ah[m].v4[0] = *(const bf16x4*)((char*)qhi_s + off0);
                    ah[m].v4[1] = *(const bf16x4*)((char*)qhi_s + off1);
                    al[m].v4[0] = *(const bf16x4*)((char*)qlo_s + off0);
                    al[m].v4[1] = *(const bf16x4*)((char*)qlo_s + off1);
                }
                Frag8 bh, bl;
                {
                    int key = wn * 16 + li;
                    int c = k2 * 32 + lg * 4;
                    unsigned swz = (unsigned)((key & 7) << 4);
                    unsigned off0 = (unsigned)((key * 64 + c) * 2) ^ swz;
                    unsigned off1 = (unsigned)((key * 64 + c + 16) * 2) ^ swz;
                    bh.v4[0] = *(const bf16x4*)((char*)kv_s + off0);
                    bh.v4[1] = *(const bf16x4*)((char*)kv_s + off1);
                    bl.v4[0] = *(const bf16x4*)((char*)kv_s + 8192 + off0);
                    bl.v4[1] = *(const bf16x4*)((char*)kv_s + 8192 + off1);
                }
#pragma unroll
                for (int m = 0; m < 2; m++) {
                    e[m] = mfma16(ah[m].v8, bh.v8, e[m]);
                    e[m] = mfma16(ah[m].v8, bl.v8, e[m]);
                    e[m] = mfma16(al[m].v8, bh.v8, e[m]);
                }
            }
        }

        // ================= online softmax =================
        float tmax[2][4];
#pragma unroll
        for (int m = 0; m < 2; m++)
#pragma unroll
            for (int r = 0; r < 4; r++) tmax[m][r] = e[m][r];
#pragma unroll
        for (int d = 1; d < 16; d <<= 1)
#pragma unroll
            for (int m = 0; m < 2; m++)
#pragma unroll
                for (int r = 0; r < 4; r++) tmax[m][r] = fmaxf(tmax[m][r], __shfl_xor(tmax[m][r], d));
        if (li == 0) {
#pragma unroll
            for (int m = 0; m < 2; m++)
#pragma unroll
                for (int r = 0; r < 4; r++) smx[wn][wm * 32 + m * 16 + lg * 4 + r] = tmax[m][r];
        }
        __syncthreads();
        float scv[2][4];
#pragma unroll
        for (int m = 0; m < 2; m++)
#pragma unroll
            for (int r = 0; r < 4; r++) {
                int row = wm * 32 + m * 16 + lg * 4 + r;
                float tm = fmaxf(fmaxf(smx[0][row], smx[1][row]), fmaxf(smx[2][row], smx[3][row]));
                float mnew = fmaxf(m_run[m][r], tm);
                scv[m][r] = __expf(m_run[m][r] - mnew);
                m_run[m][r] = mnew;
            }
        float pv[2][4], rsum[2][4];
#pragma unroll
        for (int m = 0; m < 2; m++)
#pragma unroll
            for (int r = 0; r < 4; r++) {
                float pe = __expf(e[m][r] - m_run[m][r]);
                pv[m][r] = pe;
                rsum[m][r] = pe;
            }
#pragma unroll
        for (int d = 1; d < 16; d <<= 1)
#pragma unroll
            for (int m = 0; m < 2; m++)
#pragma unroll
                for (int r = 0; r < 4; r++) rsum[m][r] += __shfl_xor(rsum[m][r], d);
        if (li == 0) {
#pragma unroll
            for (int m = 0; m < 2; m++)
#pragma unroll
                for (int r = 0; r < 4; r++) sml[wn][wm * 32 + m * 16 + lg * 4 + r] = rsum[m][r];
        }
        // write P (bf16) to LDS, swizzled
#pragma unroll
        for (int m = 0; m < 2; m++)
#pragma unroll
            for (int r = 0; r < 4; r++) {
                int ql = wm * 32 + m * 16 + lg * 4 + r;
                int kl = wn * 16 + li;
                unsigned boff = (unsigned)((ql * 64 + kl) * 2) ^ (unsigned)((ql & 7) << 4);
                *(bf16_t*)((char*)pb_s + boff) = (bf16_t)pv[m][r];
            }
        // rescale O
#pragma unroll
        for (int m = 0; m < 2; m++)
#pragma unroll
            for (int j = 0; j < 8; j++)
#pragma unroll
                for (int r = 0; r < 4; r++) o[m][j][r] *= scv[m][r];
        __syncthreads();   // sml + pb ready; kv_s free for V
#pragma unroll
        for (int m = 0; m < 2; m++)
#pragma unroll
            for (int r = 0; r < 4; r++) {
                int row = wm * 32 + m * 16 + lg * 4 + r;
                l_run[m][r] = l_run[m][r] * scv[m][r] + sml[0][row] + sml[1][row] + sml[2][row] + sml[3][row];
            }

        // ================= PV =================
        Frag8 pa[2][2];
#pragma unroll
        for (int m = 0; m < 2; m++)
#pragma unroll
            for (int k2 = 0; k2 < 2; k2++) {
                int ql = wm * 32 + m * 16 + li;
                int kp = k2 * 32 + lg * 4;
                unsigned swz = (unsigned)((ql & 7) << 4);
                pa[m][k2].v4[0] = *(const bf16x4*)((char*)pb_s + ((unsigned)((ql * 64 + kp) * 2) ^ swz));
                pa[m][k2].v4[1] = *(const bf16x4*)((char*)pb_s + ((unsigned)((ql * 64 + kp + 16) * 2) ^ swz));
            }
        bf16x8 vreg[2];
#pragma unroll
        for (int p = 0; p < 2; p++)
            vreg[p] = *(const bf16x8*)(Vb + vbase + (size_t)vcl[p] * Ln + kt + vseg[p]);
        for (int vs = 0; vs < 4; vs++) {
#pragma unroll
            for (int p = 0; p < 2; p++) {
                unsigned off = (unsigned)((vcl[p] * 64 + vseg[p]) * 2) ^ (unsigned)((vcl[p] & 7) << 4);
                *(bf16x8*)((char*)kv_s + off) = vreg[p];
            }
            if (vs < 3) {
#pragma unroll
                for (int p = 0; p < 2; p++)
                    vreg[p] = *(const bf16x8*)(Vb + vbase + (size_t)((vs + 1) * 128 + vcl[p]) * Ln + kt + vseg[p]);
            }
            __syncthreads();   // V chunk visible
#pragma unroll
            for (int jj = 0; jj < 2; jj++) {
                int cl = (wn + 4 * jj) * 16 + li;
                unsigned swz = (unsigned)((cl & 7) << 4);
#pragma unroll
                for (int k2 = 0; k2 < 2; k2++) {
                    int key = k2 * 32 + lg * 4;
                    Frag8 bv;
                    bv.v4[0] = *(const bf16x4*)((char*)kv_s + ((unsigned)((cl * 64 + key) * 2) ^ swz));
                    bv.v4[1] = *(const bf16x4*)((char*)kv_s + ((unsigned)((cl * 64 + key + 16) * 2) ^ swz));
#pragma unroll
                    for (int m = 0; m < 2; m++)
                        o[m][vs * 2 + jj] = mfma16(pa[m][k2].v8, bv.v8, o[m][vs * 2 + jj]);
                }
            }
            __syncthreads();   // MFMA reads done before next overwrite
        }
    }

    // ================= epilogue: O^T -> d_out [B][C][L] =================
#pragma unroll
    for (int m = 0; m < 2; m++)
#pragma unroll
        for (int r = 0; r < 4; r++) l_run[m][r] = 1.f / l_run[m][r];
#pragma unroll
    for (int m = 0; m < 2; m++)
#pragma unroll
        for (int j = 0; j < 8; j++) {
            int vs = j >> 1, jj = j & 1;
            int c = vs * 128 + (wn + 4 * jj) * 16 + li;
#pragma unroll
            for (int r = 0; r < 4; r++) {
                int qg = q0 + wm * 32 + m * 16 + lg * 4 + r;
                Ot[vbase + (size_t)c * Ln + qg] = o[m][j][r] * l_run[m][r];
            }
        }
}

// ---- final: out[b,c,l] = mvn(content)[b,c,l] + out[b,c,l]  (in place) ----
__global__ __launch_bounds__(256) void final_kernel(const float* __restrict__ content,
                                                    const float* __restrict__ mean_c,
                                                    const float* __restrict__ rstd_c,
                                                    float* __restrict__ out) {
    size_t gid = (size_t)blockIdx.x * 256 + threadIdx.x;
    size_t linear = gid * 4;
    int ch = (int)(linear / Ln);
    float m = mean_c[ch], rs = rstd_c[ch];
    float4 cv = *(const float4*)(content + linear);
    float4 ov = *(const float4*)(out + linear);
    ov.x += (cv.x - m) * rs;
    ov.y += (cv.y - m) * rs;
    ov.z += (cv.z - m) * rs;
    ov.w += (cv.w - m) * rs;
    *(float4*)(out + linear) = ov;
}

extern "C" void kernel_launch(void* const* d_in, const int* in_sizes, int n_in,
                              void* d_out, int out_size, void* d_ws, size_t ws_size,
                              hipStream_t stream) {
    const float* content = (const float*)d_in[0];
    const float* style   = (const float*)d_in[1];
    const float* v_w   = (const float*)d_in[2];
    const float* v_b   = (const float*)d_in[3];
    const float* vsp_w = (const float*)d_in[4];
    const float* vsp_b = (const float*)d_in[5];
    const float* k_w   = (const float*)d_in[6];
    const float* k_b   = (const float*)d_in[7];
    const float* qg_w  = (const float*)d_in[8];
    const float* qg_b  = (const float*)d_in[9];
    const float* g1_w1 = (const float*)d_in[10];
    const float* g1_b1 = (const float*)d_in[11];
    const float* g1_w2 = (const float*)d_in[12];
    const float* g1_b2 = (const float*)d_in[13];
    const float* g2_w1 = (const float*)d_in[14];
    const float* g2_b1 = (const float*)d_in[15];
    const float* g2_w2 = (const float*)d_in[16];
    const float* g2_b2 = (const float*)d_in[17];

    bf16_t* wsb = (bf16_t*)d_ws;
    bf16_t* Qhi = wsb + OFF_QHI;
    bf16_t* Qlo = wsb + OFF_QLO;
    bf16_t* Khi = wsb + OFF_KHI;
    bf16_t* Klo = wsb + OFF_KLO;
    bf16_t* Vb  = wsb + OFF_VB;
    bf16_t* wsp = wsb + OFF_WSP;
    bf16_t* Wv_hi = wsp;            bf16_t* Wv_lo = wsp + CC;
    bf16_t* Wk_hi = wsp + 2 * CC;   bf16_t* Wk_lo = wsp + 3 * CC;
    bf16_t* Wq_hi = wsp + 4 * CC;   bf16_t* Wq_lo = wsp + 5 * CC;

    float* wsf = (float*)(wsb + BF16_TOTAL);
    float* mean_s = wsf + FOFF_MEANS;
    float* rstd_s = wsf + FOFF_RSTDS;
    float* mean_c = wsf + FOFF_MEANC;
    float* rstd_c = wsf + FOFF_RSTDC;
    float* kp     = wsf + FOFF_KP;
    float* gsv    = wsf + FOFF_GSV;
    float* h1     = wsf + FOFF_H1;
    float* h2     = wsf + FOFF_H2;
    float* gamma  = wsf + FOFF_GAMMA;
    float* beta   = wsf + FOFF_BETA;

    // d_out doubles as scratch for transposed splits (2*NQK bf16 = out_size floats)
    bf16_t* XThi = (bf16_t*)d_out;
    bf16_t* XTlo = XThi + NQK;
    float* outF  = (float*)d_out;

    // 1) stats
    stats_kernel<<<dim3(Bn * Cn), 256, 0, stream>>>(style, mean_s, rstd_s);
    stats_kernel<<<dim3(Bn * Cn), 256, 0, stream>>>(content, mean_c, rstd_c);

    // 2) weight splits + style transpose-split (into d_out)
    split_w_kernel<<<dim3(CC / 2048, 3), 256, 0, stream>>>(v_w, k_w, qg_w, wsp);
    split_xt_kernel<false><<<dim3(Ln / 32, Cn / 32, Bn), 256, 0, stream>>>(style, nullptr, nullptr, XThi, XTlo);

    // 3) V conv -> bf16 [B][C][L]
    dim3 cgrid(Ln / 128, Cn / 128, Bn);
    conv_mfma_kernel<0><<<cgrid, 256, 0, stream>>>(Wv_hi, Wv_lo, XThi, XTlo, v_b, nullptr, nullptr, Vb, nullptr);

    // 4) key_pool + softmax + gsv + MLPs -> gamma, beta
    keypool_kernel<<<dim3(Ln / 256, Bn), 256, 0, stream>>>(style, vsp_w, vsp_b, mean_s, rstd_s, kp);
    softmax_kp_kernel<<<dim3(Bn), 1024, 0, stream>>>(kp);
    gsv_kernel<<<dim3(Cn, Bn), 256, 0, stream>>>(Vb, kp, gsv);
    mlp_hidden_kernel<<<dim3(Bn * Cn / 256), 256, 0, stream>>>(gsv, g1_w1, g1_b1, g2_w1, g2_b1, h1, h2);
    mlp_out_kernel<<<dim3(Bn * Cn / 256), 256, 0, stream>>>(h1, h2, g1_w2, g1_b2, g2_w2, g2_b2, gamma, beta);

    // 5) K conv (reads style split in d_out) -> Khi/Klo
    conv_mfma_kernel<1><<<cgrid, 256, 0, stream>>>(Wk_hi, Wk_lo, XThi, XTlo, k_b, nullptr, nullptr, Khi, Klo);

    // 6) content mvn transpose-split (overwrites style split in d_out), then Q conv
    split_xt_kernel<true><<<dim3(Ln / 32, Cn / 32, Bn), 256, 0, stream>>>(content, mean_c, rstd_c, XThi, XTlo);
    conv_mfma_kernel<2><<<cgrid, 256, 0, stream>>>(Wq_hi, Wq_lo, XThi, XTlo, qg_b, gamma, beta, Qhi, Qlo);

    // 7) flash attention -> O^T into d_out
    flash_kernel<<<dim3(Ln / 64, Bn), 512, 0, stream>>>(Qhi, Qlo, Khi, Klo, Vb, outF);

    // 8) final: add mvn(content) in place
    final_kernel<<<dim3((Bn * Cn * (Ln / 4)) / 256), 256, 0, stream>>>(content, mean_c, rstd_c, outF);
}